// Round 1
// 1202.937 us; speedup vs baseline: 1.0127x; 1.0127x over previous
//
#include <hip/hip_runtime.h>

// ============================================================================
// MYLSTM: functional-basis LSTM, T=49, BATCH=2048, UNITS=DIM=256, QN=9.
//
// Round 1 changes vs round 0:
//  - rec_k: 1024 threads (16 waves) -> 4 waves/SIMD (was 2). Each wave: 4 gate
//    col-tiles (64 cols), 1 proj col-tile. Latency hiding doubled.
//  - Non-temporal loads/stores on all one-shot streams (xp read, out write,
//    x read, xp write) so WcP/UP stay L2-resident (round-0 FETCH=1.29GB was
//    mostly UP/WcP re-fetches caused by streaming eviction).
//  - xproj_k: 512 threads (8 waves), wave owns 128 cols.
// ============================================================================

typedef unsigned short u16;
typedef unsigned int u32;
typedef __attribute__((ext_vector_type(8))) short bf16x8;
typedef __attribute__((ext_vector_type(4))) float f32x4;

#define T_STEPS 49
#define OUT_ROW 12544 // 49*256

__device__ __forceinline__ u16 f2b(float f) {
  u32 u = __float_as_uint(f);
  u += 0x7fffu + ((u >> 16) & 1u); // RNE
  return (u16)(u >> 16);
}
__device__ __forceinline__ float b2f(u16 h) { return __uint_as_float(((u32)h) << 16); }
__device__ __forceinline__ float sigm(float z) { return 1.0f / (1.0f + __expf(-z)); }
__device__ __forceinline__ float tanh_f(float z) {
  float e = __expf(-2.0f * fabsf(z));
  float r = (1.0f - e) / (1.0f + e); // overflow-safe: e->0 => 1
  return __builtin_copysignf(r, z);
}

// ---------------------------------------------------------------------------
// Pack weights: WcP[n][k] = W_g[k][u], WxP[n][k] = W_g[256+k][u]; n=g*256+u.
// grid 1024 blocks x 256 thr (n per block, k per thread).
__global__ void pack_w(const float* __restrict__ Wf, const float* __restrict__ Wi,
                       const float* __restrict__ Wc, const float* __restrict__ Wo,
                       u16* __restrict__ WcP, u16* __restrict__ WxP) {
  int n = blockIdx.x, k = threadIdx.x;
  int g = n >> 8, u = n & 255;
  const float* W = (g == 0) ? Wf : (g == 1) ? Wi : (g == 2) ? Wc : Wo;
  WcP[n * 256 + k] = f2b(W[k * 256 + u]);
  WxP[n * 256 + k] = f2b(W[(256 + k) * 256 + u]);
}

// ---------------------------------------------------------------------------
// U pack: UP[t][jp][j] = sum_q Q[j*2304 + jp*9 + q] * B(t,q), bf16.
// grid 49*256 blocks x 256 thr: blockIdx -> (t, jp); tid -> j.
__global__ void pack_u(const float* __restrict__ Q, u16* __restrict__ UP) {
  int bx = blockIdx.x;
  int t = bx >> 8, jp = bx & 255, j = threadIdx.x;
  const float* q = Q + j * 2304 + jp * 9;
  float tv = (float)t / 48.0f;
  float acc = q[0];
  const float SQ2 = 1.41421356237f;
#pragma unroll
  for (int i = 1; i <= 4; ++i) {
    float ang = 6.283185307179586f * (float)i * tv;
    acc += SQ2 * (sinf(ang) * q[2 * i - 1] + cosf(ang) * q[2 * i]);
  }
  UP[t * 65536 + jp * 256 + j] = f2b(acc);
}

// ---------------------------------------------------------------------------
// xproj: xp[m][n] = x[b, t0+tt, :] @ Wx[:, n], m = b*ct + tt.
// grid (2048*ct/64) wgs x 512 thr. Wave w owns cols w*128..w*128+127.
__global__ __launch_bounds__(512) void xproj_k(const float* __restrict__ x,
                                               const u16* __restrict__ WxP,
                                               u16* __restrict__ xp,
                                               int t0, int ct) {
  __shared__ u16 aLds[64][264]; // +8 pad: breaks 512B-stride bank aliasing
  int tid = threadIdx.x;
  int m0 = blockIdx.x * 64;
  // stage A: 64 rows x 256 k, fp32 -> bf16 (non-temporal: x is read once)
#pragma unroll
  for (int it = 0; it < 8; ++it) {
    int flat = it * 2048 + tid * 4;
    int r = flat >> 8, k = flat & 255;
    int rg = m0 + r;
    int b = rg / ct;
    int tt = rg - b * ct;
    const f32x4 v = __builtin_nontemporal_load(
        (const f32x4*)&x[(b * T_STEPS + (t0 + tt)) * 256 + k]);
    u16 tmp[4] = {f2b(v.x), f2b(v.y), f2b(v.z), f2b(v.w)};
    *(uint2*)&aLds[r][k] = *(uint2*)tmp;
  }
  __syncthreads();
  int w = tid >> 6, l = tid & 63, lane15 = l & 15, quad = l >> 4;
  for (int rtp = 0; rtp < 2; ++rtp) {
    bf16x8 af[2][8];
#pragma unroll
    for (int h = 0; h < 2; ++h)
#pragma unroll
      for (int ks = 0; ks < 8; ++ks)
        af[h][ks] = *(const bf16x8*)&aLds[rtp * 32 + h * 16 + lane15][ks * 32 + quad * 8];
    for (int ctl = 0; ctl < 8; ++ctl) {
      const u16* bp = WxP + (w * 128 + ctl * 16 + lane15) * 256 + quad * 8;
      bf16x8 bf[8];
#pragma unroll
      for (int ks = 0; ks < 8; ++ks) bf[ks] = *(const bf16x8*)(bp + ks * 32);
#pragma unroll
      for (int h = 0; h < 2; ++h) {
        f32x4 acc = {0.f, 0.f, 0.f, 0.f};
#pragma unroll
        for (int ks = 0; ks < 8; ++ks)
          acc = __builtin_amdgcn_mfma_f32_16x16x32_bf16(af[h][ks], bf[ks], acc, 0, 0, 0);
        int col = w * 128 + ctl * 16 + lane15;
        int rloc = rtp * 32 + h * 16 + quad * 4;
#pragma unroll
        for (int i = 0; i < 4; ++i)
          __builtin_nontemporal_store(f2b(acc[i]), &xp[(m0 + rloc + i) * 1024 + col]);
      }
    }
  }
}

// ---------------------------------------------------------------------------
// Recurrent kernel: 256 wgs x 1024 thr (16 waves). wg owns batch rows b0..b0+7.
// Per step: Z = cB @ WcP (+xp), elementwise -> c,s, h = sB @ U_t -> out.
// Wave w: gate cols w*64..+63 (4 tiles of 16), proj cols w*16..+15 (1 tile).
__global__ __launch_bounds__(1024) void rec_k(const u16* __restrict__ WcP,
                                              const u16* __restrict__ UP,
                                              const u16* __restrict__ xp,
                                              float* __restrict__ out,
                                              float* __restrict__ cstate,
                                              int tA, int tB, int cc) {
  __shared__ float cF[8][256];   // fp32 cell state
  __shared__ u16 cB[16][264];    // bf16 A-operand (rows 8..15 stay zero)
  __shared__ u16 sB[16][264];
  __shared__ float Z[8][1024];   // gate pre-activations (c-part)
  int tid = threadIdx.x;
  int b0 = blockIdx.x * 8;
  // init LDS
  for (int i = tid; i < 16 * 264; i += 1024) {
    ((u16*)cB)[i] = 0;
    ((u16*)sB)[i] = 0;
  }
  for (int i = tid; i < 2048; i += 1024) {
    int r = i >> 8, u = i & 255;
    float c0 = (tA == 0) ? 0.0f : cstate[(b0 + r) * 256 + u];
    cF[r][u] = c0;
    cB[r][u] = f2b(c0);
  }
  __syncthreads();
  int w = tid >> 6, l = tid & 63, lane15 = l & 15, quad = l >> 4;

#pragma unroll 1
  for (int t = tA; t < tB; ++t) {
    // prefetch xproj for the elementwise phase (hidden under gate GEMM).
    // Non-temporal: xp is a 205MB one-shot stream; keep it out of L2 so
    // WcP (512KB) and the UP_t window stay resident.
    u16 xpv[2][4];
#pragma unroll
    for (int p = 0; p < 2; ++p) {
      int idx = tid + p * 1024;
      int r = idx >> 8, u = idx & 255;
      const u16* xb = xp + ((b0 + r) * cc + (t - tA)) * 1024 + u;
#pragma unroll
      for (int g = 0; g < 4; ++g) xpv[p][g] = __builtin_nontemporal_load(xb + g * 256);
    }
    // ---- gate GEMM: wave w covers cols w*64 .. +63 (4 tiles of 16)
    bf16x8 af[8];
#pragma unroll
    for (int ks = 0; ks < 8; ++ks)
      af[ks] = *(const bf16x8*)&cB[lane15][ks * 32 + quad * 8];
#pragma unroll
    for (int c8 = 0; c8 < 4; ++c8) {
      f32x4 acc = {0.f, 0.f, 0.f, 0.f};
      const u16* bp = WcP + (w * 64 + c8 * 16 + lane15) * 256 + quad * 8;
#pragma unroll
      for (int ks = 0; ks < 8; ++ks)
        acc = __builtin_amdgcn_mfma_f32_16x16x32_bf16(af[ks], *(const bf16x8*)(bp + ks * 32), acc, 0, 0, 0);
      if (quad < 2) {
        int col = w * 64 + c8 * 16 + lane15;
#pragma unroll
        for (int i = 0; i < 4; ++i) Z[quad * 4 + i][col] = acc[i];
      }
    }
    __syncthreads();
    // ---- elementwise (fp32)
#pragma unroll
    for (int p = 0; p < 2; ++p) {
      int idx = tid + p * 1024;
      int r = idx >> 8, u = idx & 255;
      float zf = Z[r][u] + b2f(xpv[p][0]);
      float zi = Z[r][256 + u] + b2f(xpv[p][1]);
      float zg = Z[r][512 + u] + b2f(xpv[p][2]);
      float zo = Z[r][768 + u] + b2f(xpv[p][3]);
      float f = sigm(zf), ii = sigm(zi), gg = sigm(zg), o = tanh_f(zo);
      float cn = ii * gg + f * cF[r][u];
      cF[r][u] = cn;
      cB[r][u] = f2b(cn);
      float s = o * tanh_f(cn);
      sB[r][u] = f2b(s);
    }
    __syncthreads();
    // ---- proj GEMM: wave w covers cols w*16 .. +15 (1 tile)
    bf16x8 sf[8];
#pragma unroll
    for (int ks = 0; ks < 8; ++ks)
      sf[ks] = *(const bf16x8*)&sB[lane15][ks * 32 + quad * 8];
    {
      f32x4 acc = {0.f, 0.f, 0.f, 0.f};
      const u16* up = UP + t * 65536 + (w * 16 + lane15) * 256 + quad * 8;
#pragma unroll
      for (int ks = 0; ks < 8; ++ks)
        acc = __builtin_amdgcn_mfma_f32_16x16x32_bf16(sf[ks], *(const bf16x8*)(up + ks * 32), acc, 0, 0, 0);
      if (quad < 2) {
        int col = w * 16 + lane15;
#pragma unroll
        for (int i = 0; i < 4; ++i)
          __builtin_nontemporal_store(
              tanh_f(acc[i]), &out[(b0 + quad * 4 + i) * OUT_ROW + t * 256 + col]);
      }
    }
    // no barrier needed here: next gate GEMM's Z writes / cB reads are fenced
    // by this step's two barriers (see hazard analysis in session notes).
  }
  if (tB < T_STEPS) {
    for (int i = tid; i < 2048; i += 1024) {
      int r = i >> 8, u = i & 255;
      cstate[(b0 + r) * 256 + u] = cF[r][u];
    }
  }
}

// ---------------------------------------------------------------------------
extern "C" void kernel_launch(void* const* d_in, const int* in_sizes, int n_in,
                              void* d_out, int out_size, void* d_ws, size_t ws_size,
                              hipStream_t stream) {
  const float* x = (const float*)d_in[0];
  const float* Wf = (const float*)d_in[1];
  const float* Wi = (const float*)d_in[2];
  const float* Wc = (const float*)d_in[3];
  const float* Wo = (const float*)d_in[4];
  const float* Q = (const float*)d_in[5];
  float* out = (float*)d_out;

  char* p = (char*)d_ws;
  u16* WcP = (u16*)p;           p += (size_t)1024 * 256 * 2;        // 512 KB
  u16* WxP = (u16*)p;           p += (size_t)1024 * 256 * 2;        // 512 KB
  u16* UP = (u16*)p;            p += (size_t)49 * 256 * 256 * 2;    // 6.13 MB
  float* cstate = (float*)p;    p += (size_t)2048 * 256 * 4;        // 2 MB
  u16* xpb = (u16*)p;
  size_t used = (size_t)(p - (char*)d_ws);
  size_t rem = (ws_size > used) ? (ws_size - used) : 0;
  const size_t perT = (size_t)2048 * 1024 * 2; // 4 MB per timestep of xproj
  int CT = (int)(rem / perT);
  if (CT > 49) CT = 49;
  if (CT < 1) CT = 1; // require ~14 MB of ws minimum

  pack_w<<<dim3(1024), dim3(256), 0, stream>>>(Wf, Wi, Wc, Wo, WcP, WxP);
  pack_u<<<dim3(49 * 256), dim3(256), 0, stream>>>(Q, UP);

  for (int t0 = 0; t0 < T_STEPS; t0 += CT) {
    int cc = (T_STEPS - t0 < CT) ? (T_STEPS - t0) : CT;
    xproj_k<<<dim3(2048 * cc / 64), dim3(512), 0, stream>>>(x, WxP, xpb, t0, cc);
    rec_k<<<dim3(256), dim3(1024), 0, stream>>>(WcP, UP, xpb, out, cstate, t0, t0 + cc, cc);
  }
}